// Round 6
// baseline (166.460 us; speedup 1.0000x reference)
//
#include <hip/hip_runtime.h>

typedef __attribute__((ext_vector_type(8))) short bf16x8;
typedef __attribute__((ext_vector_type(4))) float f32x4;

#define BB 4
#define NN 32
#define CC 32
#define HWD 4096
#define AROW ((size_t)CC * HWD)   // stride between n-rows (floats)

// Instrumentation reps (idempotent bodies; output identical to single-rep)
#define GRAM_REPS 6
#define SM_REPS 150
#define PV_REPS 4

__device__ __forceinline__ unsigned cvt_pk_bf16(float lo, float hi) {
    unsigned r;
    asm("v_cvt_pk_bf16_f32 %0, %1, %2" : "=v"(r) : "v"(lo), "v"(hi));
    return r;
}

__device__ __forceinline__ bf16x8 pack8(float4 a, float4 b) {
    union { unsigned u[4]; bf16x8 v; } u;
    u.u[0] = cvt_pk_bf16(a.x, a.y);
    u.u[1] = cvt_pk_bf16(a.z, a.w);
    u.u[2] = cvt_pk_bf16(b.x, b.y);
    u.u[3] = cvt_pk_bf16(b.z, b.w);
    return u.v;
}

// ---- Kernel 1: Gram partials via MFMA, frags straight from global (R2, proven) ----
__global__ __launch_bounds__(256) void k_gram(const float* __restrict__ x,
                                              float* __restrict__ Gp) {
    const int bid = blockIdx.x;
    const int s   = bid & 7;
    const int bc  = bid >> 3;
    const int b   = bc >> 5, c = bc & 31;
    const int tid = threadIdx.x;
    const int w   = tid >> 6, l = tid & 63;
    const int r   = l & 15, g = l >> 4;

    __shared__ float red[4][64][16];

    const float* xb = x + ((size_t)b * NN * CC + c) * HWD;
    const int hwbase = s * 512 + w * 128;
    const float* p0 = xb + (size_t)r        * AROW + hwbase + 8 * g;
    const float* p1 = xb + (size_t)(r + 16) * AROW + hwbase + 8 * g;

#pragma clang loop unroll(disable)
    for (int rep = 0; rep < GRAM_REPS; ++rep) {
        __syncthreads();   // red[] reuse across reps

        f32x4 acc[2][2];
#pragma unroll
        for (int i = 0; i < 2; ++i)
#pragma unroll
            for (int j = 0; j < 2; ++j)
#pragma unroll
                for (int q = 0; q < 4; ++q) acc[i][j][q] = 0.f;

#pragma unroll
        for (int ch = 0; ch < 4; ++ch) {
            const float4 a0 = *(const float4*)(p0 + ch * 32);
            const float4 a1 = *(const float4*)(p0 + ch * 32 + 4);
            const float4 b0 = *(const float4*)(p1 + ch * 32);
            const float4 b1 = *(const float4*)(p1 + ch * 32 + 4);
            const bf16x8 F0 = pack8(a0, a1);
            const bf16x8 F1 = pack8(b0, b1);
            acc[0][0] = __builtin_amdgcn_mfma_f32_16x16x32_bf16(F0, F0, acc[0][0], 0, 0, 0);
            acc[0][1] = __builtin_amdgcn_mfma_f32_16x16x32_bf16(F0, F1, acc[0][1], 0, 0, 0);
            acc[1][0] = __builtin_amdgcn_mfma_f32_16x16x32_bf16(F1, F0, acc[1][0], 0, 0, 0);
            acc[1][1] = __builtin_amdgcn_mfma_f32_16x16x32_bf16(F1, F1, acc[1][1], 0, 0, 0);
        }

#pragma unroll
        for (int ta = 0; ta < 2; ++ta)
#pragma unroll
            for (int tf = 0; tf < 2; ++tf)
#pragma unroll
                for (int q = 0; q < 4; ++q)
                    red[w][l][(ta * 2 + tf) * 4 + q] = acc[ta][tf][q];
        __syncthreads();

        const int a   = tid >> 3;
        const int f0  = 4 * (tid & 7);
        const int lg  = ((a >> 2) & 3) * 16 + (f0 & 15);
        const int reg = ((a >> 4) * 2 + (f0 >> 4)) * 4 + (a & 3);
        float sv[4];
#pragma unroll
        for (int j = 0; j < 4; ++j) {
            float v = 0.f;
#pragma unroll
            for (int ww = 0; ww < 4; ++ww) v += red[ww][lg + j][reg];
            sv[j] = v;
        }
        *(float4*)&Gp[(size_t)bid * 1024 + 4 * tid] = make_float4(sv[0], sv[1], sv[2], sv[3]);

        asm volatile("" ::: "memory");
    }
}

// ---- Kernel 2: reduce 8 splits + scale + softmax + fold wv, emit bf16 Ahat (R2, proven) ----
__global__ __launch_bounds__(256) void k_softmax(const float* __restrict__ Gp,
                                                 const float* __restrict__ w,
                                                 unsigned short* __restrict__ Ahat) {
    const int bc = blockIdx.x;
    const int c  = bc & 31;
    const int t  = threadIdx.x;
    const int a  = t >> 3, fo = 4 * (t & 7);

#pragma clang loop unroll(disable)
    for (int rep = 0; rep < SM_REPS; ++rep) {
        float gs[4] = {0.f, 0.f, 0.f, 0.f};
#pragma unroll
        for (int s = 0; s < 8; ++s) {
            const float4 v = *(const float4*)&Gp[(size_t)(bc * 8 + s) * 1024 + a * 32 + fo];
            gs[0] += v.x; gs[1] += v.y; gs[2] += v.z; gs[3] += v.w;
        }
        const float wq = w[(a * CC + c) * 3] * 0.015625f;   // 1/sqrt(4096)
        float S[4];
#pragma unroll
        for (int j = 0; j < 4; ++j)
            S[j] = wq * w[((fo + j) * CC + c) * 3 + 1] * gs[j];

        float m = fmaxf(fmaxf(S[0], S[1]), fmaxf(S[2], S[3]));
#pragma unroll
        for (int o = 1; o < 8; o <<= 1) m = fmaxf(m, __shfl_xor(m, o, 64));
        float e[4], sum = 0.f;
#pragma unroll
        for (int j = 0; j < 4; ++j) { e[j] = __expf(S[j] - m); sum += e[j]; }
#pragma unroll
        for (int o = 1; o < 8; o <<= 1) sum += __shfl_xor(sum, o, 64);
        const float inv = 1.f / sum;

        float o0 = e[0] * inv * w[((fo + 0) * CC + c) * 3 + 2];
        float o1 = e[1] * inv * w[((fo + 1) * CC + c) * 3 + 2];
        float o2 = e[2] * inv * w[((fo + 2) * CC + c) * 3 + 2];
        float o3 = e[3] * inv * w[((fo + 3) * CC + c) * 3 + 2];
        uint2 pk = make_uint2(cvt_pk_bf16(o0, o1), cvt_pk_bf16(o2, o3));
        *(uint2*)&Ahat[(size_t)bc * 1024 + a * 32 + fo] = pk;

        asm volatile("" ::: "memory");
    }
}

// ---- Kernel 3: PV with coalesced LDS staging; Ahat from global (no fused softmax) ----
// grid 2048 = 128 bc x 16 chunks(256 hw); block 256 (4 waves)
__global__ __launch_bounds__(256) void k_pv(const float* __restrict__ x,
                                            const unsigned short* __restrict__ Ahat,
                                            float* __restrict__ out) {
    const int bid   = blockIdx.x;
    const int chunk = bid & 15;
    const int bc    = bid >> 4;
    const int b     = bc >> 5, c = bc & 31;
    const int tid   = threadIdx.x;
    const int wv    = tid >> 6, l = tid & 63;
    const int r     = l & 15, g = l >> 4;

    __shared__ unsigned xt[256][16];   // [hw][fpair dword], col = p ^ (hw&12)
    const f32x4 zero = {0.f, 0.f, 0.f, 0.f};

#pragma clang loop unroll(disable)
    for (int rep = 0; rep < PV_REPS; ++rep) {
        __syncthreads();   // xt reuse across reps

        // stage x[f=0..31][hw chunk of 256]: coalesced float4 loads, swizzled LDS
        {
            const int p = tid >> 4;          // f-pair index 0..15 (f = 2p, 2p+1)
            const int q = tid & 15;
            const float* xr0 = x + ((size_t)(b * NN + 2 * p) * CC + c) * HWD + chunk * 256;
            const float* xr1 = xr0 + AROW;
#pragma unroll
            for (int k = 0; k < 4; ++k) {
                const int hwc = 4 * (q + 16 * k);
                const float4 fa = *(const float4*)(xr0 + hwc);
                const float4 fb = *(const float4*)(xr1 + hwc);
                const float av[4] = {fa.x, fa.y, fa.z, fa.w};
                const float bv[4] = {fb.x, fb.y, fb.z, fb.w};
#pragma unroll
                for (int i = 0; i < 4; ++i) {
                    const int hw = hwc + i;
                    xt[hw][p ^ (hw & 12)] = cvt_pk_bf16(av[i], bv[i]);
                }
            }
        }

        // A-frags: bf16 Ahat rows, contiguous 16B (L2-resident, 2KB/block)
        const unsigned short* ab = Ahat + (size_t)bc * 1024;
        const bf16x8 A0 = *(const bf16x8*)(ab + r * 32 + 8 * g);
        const bf16x8 A1 = *(const bf16x8*)(ab + (r + 16) * 32 + 8 * g);

        __syncthreads();

#pragma unroll
        for (int ht = 0; ht < 4; ++ht) {
            const int hw = wv * 64 + ht * 16 + r;
            const bf16x8 B = *(const bf16x8*)&xt[hw][4 * (g ^ ((hw >> 2) & 3))];
            f32x4 d0 = __builtin_amdgcn_mfma_f32_16x16x32_bf16(A0, B, zero, 0, 0, 0);
            f32x4 d1 = __builtin_amdgcn_mfma_f32_16x16x32_bf16(A1, B, zero, 0, 0, 0);

            const size_t hwg = (size_t)chunk * 256 + hw;
#pragma unroll
            for (int q2 = 0; q2 < 4; ++q2) {
                const int a0r = g * 4 + q2;
                out[(((size_t)a0r * BB + b) * CC + c) * HWD + hwg]        = d0[q2];
                out[(((size_t)(a0r + 16) * BB + b) * CC + c) * HWD + hwg] = d1[q2];
            }
        }

        asm volatile("" ::: "memory");
    }
}

extern "C" void kernel_launch(void* const* d_in, const int* in_sizes, int n_in,
                              void* d_out, int out_size, void* d_ws, size_t ws_size,
                              hipStream_t stream) {
    const float* x = (const float*)d_in[0];
    const float* w = (const float*)d_in[1];
    float* outp = (float*)d_out;
    float* Gp = (float*)d_ws;                                                  // 4 MB
    unsigned short* Ahat = (unsigned short*)((char*)d_ws + (size_t)4 * 1024 * 1024); // 256 KB

    hipLaunchKernelGGL(k_gram,    dim3(1024), dim3(256), 0, stream, x, Gp);
    hipLaunchKernelGGL(k_softmax, dim3(128),  dim3(256), 0, stream, Gp, w, Ahat);
    hipLaunchKernelGGL(k_pv,      dim3(2048), dim3(256), 0, stream, x, Ahat, outp);
}

// Round 7
// 147.159 us; speedup vs baseline: 1.1312x; 1.1312x over previous
//
#include <hip/hip_runtime.h>

typedef __attribute__((ext_vector_type(8))) short bf16x8;
typedef __attribute__((ext_vector_type(4))) float f32x4;

#define BB 4
#define NN 32
#define CC 32
#define HWD 4096
#define AROW ((size_t)CC * HWD)   // stride between n-rows (floats)

#define GP_BYTES   ((size_t)4 * 1024 * 1024)          // 1024 blocks * 1024 f32
#define AHAT_BYTES ((size_t)256 * 1024)               // 128 bc * 512 dwords
#define CTRL_OFF   (GP_BYTES + AHAT_BYTES)

__device__ __forceinline__ unsigned cvt_pk_bf16(float lo, float hi) {
    unsigned r;
    asm("v_cvt_pk_bf16_f32 %0, %1, %2" : "=v"(r) : "v"(lo), "v"(hi));
    return r;
}

__device__ __forceinline__ bf16x8 pack8(float4 a, float4 b) {
    union { unsigned u[4]; bf16x8 v; } u;
    u.u[0] = cvt_pk_bf16(a.x, a.y);
    u.u[1] = cvt_pk_bf16(a.z, a.w);
    u.u[2] = cvt_pk_bf16(b.x, b.y);
    u.u[3] = cvt_pk_bf16(b.z, b.w);
    return u.v;
}

// Single fused kernel. 1024 blocks = 128 bc x 8 s. Phase A: gram split.
// Fan-in: last block per bc does softmax -> Ahat, sets flag. Phase B: all
// blocks spin on their bc flag, then pv for chunks {2s, 2s+1}.
// Co-residency: 4 blocks/CU guaranteed (16KB LDS, <=128 VGPR) -> all 1024
// resident -> spin cannot deadlock.
__global__ __launch_bounds__(256, 4) void k_all(const float* __restrict__ x,
                                                const float* __restrict__ w,
                                                float* __restrict__ Gp,
                                                unsigned* __restrict__ Ahat,
                                                unsigned* __restrict__ cnt,
                                                unsigned* __restrict__ flag,
                                                float* __restrict__ out) {
    const int bid = blockIdx.x;       // 0..1023
    const int s   = bid & 7;
    const int bc  = bid >> 3;
    const int b   = bc >> 5, c = bc & 31;
    const int tid = threadIdx.x;
    const int wv  = tid >> 6, l = tid & 63;
    const int r   = l & 15, g = l >> 4;

    __shared__ union {
        float red[4][64][16];      // gram block-reduce (16 KB)
        unsigned xt[256][16];      // pv staging tile (16 KB)
    } sm;
    __shared__ unsigned is_last;

    // ---------------- Phase A: gram split (R5-proven math) ----------------
    {
        const float* xb = x + ((size_t)b * NN * CC + c) * HWD;
        const int hwbase = s * 512 + wv * 128;
        const float* p0 = xb + (size_t)r        * AROW + hwbase + 8 * g;
        const float* p1 = xb + (size_t)(r + 16) * AROW + hwbase + 8 * g;

        f32x4 acc[2][2];
#pragma unroll
        for (int i = 0; i < 2; ++i)
#pragma unroll
            for (int j = 0; j < 2; ++j)
#pragma unroll
                for (int q = 0; q < 4; ++q) acc[i][j][q] = 0.f;

#pragma unroll
        for (int ch = 0; ch < 4; ++ch) {
            const float4 a0 = *(const float4*)(p0 + ch * 32);
            const float4 a1 = *(const float4*)(p0 + ch * 32 + 4);
            const float4 b0 = *(const float4*)(p1 + ch * 32);
            const float4 b1 = *(const float4*)(p1 + ch * 32 + 4);
            const bf16x8 F0 = pack8(a0, a1);
            const bf16x8 F1 = pack8(b0, b1);
            acc[0][0] = __builtin_amdgcn_mfma_f32_16x16x32_bf16(F0, F0, acc[0][0], 0, 0, 0);
            acc[0][1] = __builtin_amdgcn_mfma_f32_16x16x32_bf16(F0, F1, acc[0][1], 0, 0, 0);
            acc[1][0] = __builtin_amdgcn_mfma_f32_16x16x32_bf16(F1, F0, acc[1][0], 0, 0, 0);
            acc[1][1] = __builtin_amdgcn_mfma_f32_16x16x32_bf16(F1, F1, acc[1][1], 0, 0, 0);
        }

#pragma unroll
        for (int ta = 0; ta < 2; ++ta)
#pragma unroll
            for (int tf = 0; tf < 2; ++tf)
#pragma unroll
                for (int q = 0; q < 4; ++q)
                    sm.red[wv][l][(ta * 2 + tf) * 4 + q] = acc[ta][tf][q];
        __syncthreads();

        const int a   = tid >> 3;
        const int f0  = 4 * (tid & 7);
        const int lg  = ((a >> 2) & 3) * 16 + (f0 & 15);
        const int reg = ((a >> 4) * 2 + (f0 >> 4)) * 4 + (a & 3);
        float sv[4];
#pragma unroll
        for (int j = 0; j < 4; ++j) {
            float v = 0.f;
#pragma unroll
            for (int ww = 0; ww < 4; ++ww) v += sm.red[ww][lg + j][reg];
            sv[j] = v;
        }
        *(float4*)&Gp[(size_t)bid * 1024 + 4 * tid] = make_float4(sv[0], sv[1], sv[2], sv[3]);
    }

    // ---------------- Fan-in: last of 8 sibling blocks does softmax ----------------
    __syncthreads();   // drains the Gp stores (vmcnt 0 before barrier)
    if (tid == 0) {
        __threadfence();                              // publish block's Gp split
        unsigned old = atomicAdd(&cnt[bc], 1u);       // device-scope
        is_last = (old == 7u) ? 1u : 0u;
    }
    __syncthreads();

    if (is_last) {
        const int a = tid >> 3, fo = 4 * (tid & 7);
        float gs[4] = {0.f, 0.f, 0.f, 0.f};
#pragma unroll
        for (int s2 = 0; s2 < 8; ++s2) {
            const float* gp = &Gp[(size_t)(bc * 8 + s2) * 1024 + a * 32 + fo];
            gs[0] += __hip_atomic_load(gp + 0, __ATOMIC_RELAXED, __HIP_MEMORY_SCOPE_AGENT);
            gs[1] += __hip_atomic_load(gp + 1, __ATOMIC_RELAXED, __HIP_MEMORY_SCOPE_AGENT);
            gs[2] += __hip_atomic_load(gp + 2, __ATOMIC_RELAXED, __HIP_MEMORY_SCOPE_AGENT);
            gs[3] += __hip_atomic_load(gp + 3, __ATOMIC_RELAXED, __HIP_MEMORY_SCOPE_AGENT);
        }
        const float wq = w[(a * CC + c) * 3] * 0.015625f;   // 1/sqrt(4096)
        float S[4];
#pragma unroll
        for (int j = 0; j < 4; ++j)
            S[j] = wq * w[((fo + j) * CC + c) * 3 + 1] * gs[j];

        float m = fmaxf(fmaxf(S[0], S[1]), fmaxf(S[2], S[3]));
#pragma unroll
        for (int o = 1; o < 8; o <<= 1) m = fmaxf(m, __shfl_xor(m, o, 64));
        float e[4], sum = 0.f;
#pragma unroll
        for (int j = 0; j < 4; ++j) { e[j] = __expf(S[j] - m); sum += e[j]; }
#pragma unroll
        for (int o = 1; o < 8; o <<= 1) sum += __shfl_xor(sum, o, 64);
        const float inv = 1.f / sum;

        const float o0 = e[0] * inv * w[((fo + 0) * CC + c) * 3 + 2];
        const float o1 = e[1] * inv * w[((fo + 1) * CC + c) * 3 + 2];
        const float o2 = e[2] * inv * w[((fo + 2) * CC + c) * 3 + 2];
        const float o3 = e[3] * inv * w[((fo + 3) * CC + c) * 3 + 2];
        unsigned* ad = Ahat + (size_t)bc * 512 + a * 16 + 2 * (tid & 7);
        __hip_atomic_store(ad + 0, cvt_pk_bf16(o0, o1), __ATOMIC_RELAXED, __HIP_MEMORY_SCOPE_AGENT);
        __hip_atomic_store(ad + 1, cvt_pk_bf16(o2, o3), __ATOMIC_RELAXED, __HIP_MEMORY_SCOPE_AGENT);
        __syncthreads();   // all Ahat stores complete
        if (tid == 0) {
            __threadfence();
            __hip_atomic_store(&flag[bc], 1u, __ATOMIC_RELEASE, __HIP_MEMORY_SCOPE_AGENT);
        }
    }

    // ---------------- Spin until this bc's Ahat is published ----------------
    if (tid == 0) {
        while (__hip_atomic_load(&flag[bc], __ATOMIC_ACQUIRE, __HIP_MEMORY_SCOPE_AGENT) == 0u)
            __builtin_amdgcn_s_sleep(2);
    }
    __syncthreads();

    // ---------------- A-frags (agent-coherent dword loads, 2 KB per bc) ----------------
    union { unsigned u[4]; bf16x8 v; } ua0, ua1;
    {
        const unsigned* ad = Ahat + (size_t)bc * 512;
#pragma unroll
        for (int i = 0; i < 4; ++i) {
            ua0.u[i] = __hip_atomic_load(ad + r * 16 + 4 * g + i,
                                         __ATOMIC_RELAXED, __HIP_MEMORY_SCOPE_AGENT);
            ua1.u[i] = __hip_atomic_load(ad + (r + 16) * 16 + 4 * g + i,
                                         __ATOMIC_RELAXED, __HIP_MEMORY_SCOPE_AGENT);
        }
    }

    // ---------------- Phase B: pv for chunks 2s, 2s+1 (R5-proven math) ----------------
    const f32x4 zero = {0.f, 0.f, 0.f, 0.f};
#pragma clang loop unroll(disable)
    for (int ck = 0; ck < 2; ++ck) {
        const int chunk = 2 * s + ck;
        __syncthreads();   // sm.xt free (phase A / previous chunk done)

        {
            const int p = tid >> 4;          // f-pair index 0..15
            const int q = tid & 15;
            const float* xr0 = x + ((size_t)(b * NN + 2 * p) * CC + c) * HWD + chunk * 256;
            const float* xr1 = xr0 + AROW;
#pragma unroll
            for (int k = 0; k < 4; ++k) {
                const int hwc = 4 * (q + 16 * k);
                const float4 fa = *(const float4*)(xr0 + hwc);
                const float4 fb = *(const float4*)(xr1 + hwc);
                const float av[4] = {fa.x, fa.y, fa.z, fa.w};
                const float bv[4] = {fb.x, fb.y, fb.z, fb.w};
#pragma unroll
                for (int i = 0; i < 4; ++i) {
                    const int hw = hwc + i;
                    sm.xt[hw][p ^ (hw & 12)] = cvt_pk_bf16(av[i], bv[i]);
                }
            }
        }
        __syncthreads();

#pragma unroll
        for (int ht = 0; ht < 4; ++ht) {
            const int hw = wv * 64 + ht * 16 + r;
            const bf16x8 B = *(const bf16x8*)&sm.xt[hw][4 * (g ^ ((hw >> 2) & 3))];
            f32x4 d0 = __builtin_amdgcn_mfma_f32_16x16x32_bf16(ua0.v, B, zero, 0, 0, 0);
            f32x4 d1 = __builtin_amdgcn_mfma_f32_16x16x32_bf16(ua1.v, B, zero, 0, 0, 0);

            const size_t hwg = (size_t)chunk * 256 + hw;
#pragma unroll
            for (int q2 = 0; q2 < 4; ++q2) {
                const int a0r = g * 4 + q2;
                out[(((size_t)a0r * BB + b) * CC + c) * HWD + hwg]        = d0[q2];
                out[(((size_t)(a0r + 16) * BB + b) * CC + c) * HWD + hwg] = d1[q2];
            }
        }
    }
}

extern "C" void kernel_launch(void* const* d_in, const int* in_sizes, int n_in,
                              void* d_out, int out_size, void* d_ws, size_t ws_size,
                              hipStream_t stream) {
    const float* x = (const float*)d_in[0];
    const float* w = (const float*)d_in[1];
    float* outp = (float*)d_out;
    float* Gp      = (float*)d_ws;
    unsigned* Ahat = (unsigned*)((char*)d_ws + GP_BYTES);
    unsigned* ctrl = (unsigned*)((char*)d_ws + CTRL_OFF);
    unsigned* cnt  = ctrl;          // 128 uints
    unsigned* flag = ctrl + 128;    // 128 uints

    // zero the fan-in counters/flags (also clears the 0xAA poison)
    hipMemsetAsync((void*)ctrl, 0, 1024, stream);
    hipLaunchKernelGGL(k_all, dim3(1024), dim3(256), 0, stream,
                       x, w, Gp, Ahat, cnt, flag, outp);
}

// Round 8
// 45.586 us; speedup vs baseline: 3.6516x; 3.2282x over previous
//
#include <hip/hip_runtime.h>

typedef __attribute__((ext_vector_type(8))) short bf16x8;
typedef __attribute__((ext_vector_type(4))) float f32x4;

#define BB 4
#define NN 32
#define CC 32
#define HWD 4096
#define AROW ((size_t)CC * HWD)   // stride between n-rows (floats)

__device__ __forceinline__ unsigned cvt_pk_bf16(float lo, float hi) {
    unsigned r;
    asm("v_cvt_pk_bf16_f32 %0, %1, %2" : "=v"(r) : "v"(lo), "v"(hi));
    return r;
}

__device__ __forceinline__ bf16x8 pack8(float4 a, float4 b) {
    union { unsigned u[4]; bf16x8 v; } u;
    u.u[0] = cvt_pk_bf16(a.x, a.y);
    u.u[1] = cvt_pk_bf16(a.z, a.w);
    u.u[2] = cvt_pk_bf16(b.x, b.y);
    u.u[3] = cvt_pk_bf16(b.z, b.w);
    return u.v;
}

// ---- Kernel 1: Gram partials via MFMA, frags straight from global (R2, proven) ----
// grid 1024 = 128 bc x 8 splits(512 hw); block 256 (4 waves, each 128 hw)
__global__ __launch_bounds__(256) void k_gram(const float* __restrict__ x,
                                              float* __restrict__ Gp) {
    const int bid = blockIdx.x;
    const int s   = bid & 7;
    const int bc  = bid >> 3;
    const int b   = bc >> 5, c = bc & 31;
    const int tid = threadIdx.x;
    const int w   = tid >> 6, l = tid & 63;
    const int r   = l & 15, g = l >> 4;

    const float* xb = x + ((size_t)b * NN * CC + c) * HWD;
    const int hwbase = s * 512 + w * 128;
    const float* p0 = xb + (size_t)r        * AROW + hwbase + 8 * g;
    const float* p1 = xb + (size_t)(r + 16) * AROW + hwbase + 8 * g;

    f32x4 acc[2][2];
#pragma unroll
    for (int i = 0; i < 2; ++i)
#pragma unroll
        for (int j = 0; j < 2; ++j)
#pragma unroll
            for (int q = 0; q < 4; ++q) acc[i][j][q] = 0.f;

#pragma unroll
    for (int ch = 0; ch < 4; ++ch) {
        const float4 a0 = *(const float4*)(p0 + ch * 32);
        const float4 a1 = *(const float4*)(p0 + ch * 32 + 4);
        const float4 b0 = *(const float4*)(p1 + ch * 32);
        const float4 b1 = *(const float4*)(p1 + ch * 32 + 4);
        const bf16x8 F0 = pack8(a0, a1);
        const bf16x8 F1 = pack8(b0, b1);
        acc[0][0] = __builtin_amdgcn_mfma_f32_16x16x32_bf16(F0, F0, acc[0][0], 0, 0, 0);
        acc[0][1] = __builtin_amdgcn_mfma_f32_16x16x32_bf16(F0, F1, acc[0][1], 0, 0, 0);
        acc[1][0] = __builtin_amdgcn_mfma_f32_16x16x32_bf16(F1, F0, acc[1][0], 0, 0, 0);
        acc[1][1] = __builtin_amdgcn_mfma_f32_16x16x32_bf16(F1, F1, acc[1][1], 0, 0, 0);
    }

    __shared__ float red[4][64][16];
#pragma unroll
    for (int ta = 0; ta < 2; ++ta)
#pragma unroll
        for (int tf = 0; tf < 2; ++tf)
#pragma unroll
            for (int q = 0; q < 4; ++q)
                red[w][l][(ta * 2 + tf) * 4 + q] = acc[ta][tf][q];
    __syncthreads();

    const int a   = tid >> 3;
    const int f0  = 4 * (tid & 7);
    const int lg  = ((a >> 2) & 3) * 16 + (f0 & 15);
    const int reg = ((a >> 4) * 2 + (f0 >> 4)) * 4 + (a & 3);
    float sv[4];
#pragma unroll
    for (int j = 0; j < 4; ++j) {
        float v = 0.f;
#pragma unroll
        for (int ww = 0; ww < 4; ++ww) v += red[ww][lg + j][reg];
        sv[j] = v;
    }
    *(float4*)&Gp[(size_t)bid * 1024 + 4 * tid] = make_float4(sv[0], sv[1], sv[2], sv[3]);
}

// ---- Kernel 2: reduce 8 splits + scale + softmax + fold wv, emit bf16 Ahat (proven) ----
__global__ __launch_bounds__(256) void k_softmax(const float* __restrict__ Gp,
                                                 const float* __restrict__ w,
                                                 unsigned short* __restrict__ Ahat) {
    const int bc = blockIdx.x;
    const int c  = bc & 31;
    const int t  = threadIdx.x;
    const int a  = t >> 3, fo = 4 * (t & 7);

    float gs[4] = {0.f, 0.f, 0.f, 0.f};
#pragma unroll
    for (int s = 0; s < 8; ++s) {
        const float4 v = *(const float4*)&Gp[(size_t)(bc * 8 + s) * 1024 + a * 32 + fo];
        gs[0] += v.x; gs[1] += v.y; gs[2] += v.z; gs[3] += v.w;
    }
    const float wq = w[(a * CC + c) * 3] * 0.015625f;   // 1/sqrt(4096)
    float S[4];
#pragma unroll
    for (int j = 0; j < 4; ++j)
        S[j] = wq * w[((fo + j) * CC + c) * 3 + 1] * gs[j];

    float m = fmaxf(fmaxf(S[0], S[1]), fmaxf(S[2], S[3]));
#pragma unroll
    for (int o = 1; o < 8; o <<= 1) m = fmaxf(m, __shfl_xor(m, o, 64));
    float e[4], sum = 0.f;
#pragma unroll
    for (int j = 0; j < 4; ++j) { e[j] = __expf(S[j] - m); sum += e[j]; }
#pragma unroll
    for (int o = 1; o < 8; o <<= 1) sum += __shfl_xor(sum, o, 64);
    const float inv = 1.f / sum;

    float o0 = e[0] * inv * w[((fo + 0) * CC + c) * 3 + 2];
    float o1 = e[1] * inv * w[((fo + 1) * CC + c) * 3 + 2];
    float o2 = e[2] * inv * w[((fo + 2) * CC + c) * 3 + 2];
    float o3 = e[3] * inv * w[((fo + 3) * CC + c) * 3 + 2];
    uint2 pk = make_uint2(cvt_pk_bf16(o0, o1), cvt_pk_bf16(o2, o3));
    *(uint2*)&Ahat[(size_t)bc * 1024 + a * 32 + fo] = pk;
}

// ---- Kernel 3: PV, swapped-operand MFMA -> D[hw][a] -> float4 nontemporal stores ----
// grid 2048 = 128 bc x 16 chunks(256 hw); block 256 (4 waves)
__global__ __launch_bounds__(256) void k_pv(const float* __restrict__ x,
                                            const unsigned short* __restrict__ Ahat,
                                            float* __restrict__ out) {
    const int bid   = blockIdx.x;
    const int chunk = bid & 15;
    const int bc    = bid >> 4;
    const int b     = bc >> 5, c = bc & 31;
    const int tid   = threadIdx.x;
    const int wv    = tid >> 6, l = tid & 63;
    const int r     = l & 15, g = l >> 4;

    __shared__ unsigned xt[256][16];   // [hw][fpair dword], col = p ^ (hw&12)

    // stage x[f=0..31][hw chunk of 256]: coalesced float4 loads, swizzled LDS
    {
        const int p = tid >> 4;          // f-pair index 0..15 (f = 2p, 2p+1)
        const int q = tid & 15;
        const float* xr0 = x + ((size_t)(b * NN + 2 * p) * CC + c) * HWD + chunk * 256;
        const float* xr1 = xr0 + AROW;
#pragma unroll
        for (int k = 0; k < 4; ++k) {
            const int hwc = 4 * (q + 16 * k);
            const float4 fa = *(const float4*)(xr0 + hwc);
            const float4 fb = *(const float4*)(xr1 + hwc);
            const float av[4] = {fa.x, fa.y, fa.z, fa.w};
            const float bv[4] = {fb.x, fb.y, fb.z, fb.w};
#pragma unroll
            for (int i = 0; i < 4; ++i) {
                const int hw = hwc + i;
                xt[hw][p ^ (hw & 12)] = cvt_pk_bf16(av[i], bv[i]);
            }
        }
    }

    // B-op frags: Ahat rows (lane&15 = col a), contiguous 16B, L2-resident
    const unsigned short* ab = Ahat + (size_t)bc * 1024;
    const bf16x8 A0 = *(const bf16x8*)(ab + r * 32 + 8 * g);        // a = r
    const bf16x8 A1 = *(const bf16x8*)(ab + (r + 16) * 32 + 8 * g); // a = r+16

    __syncthreads();

    const f32x4 zero = {0.f, 0.f, 0.f, 0.f};
#pragma unroll
    for (int ht = 0; ht < 4; ++ht) {
        const int hwrow = wv * 64 + ht * 16;          // tile base (16 hw rows)
        const int hw    = hwrow + r;
        // A-op frag: lane&15 = row hw, k = f (same LDS address as before)
        const bf16x8 Xf = *(const bf16x8*)&xt[hw][4 * (g ^ ((hw >> 2) & 3))];
        f32x4 d0 = __builtin_amdgcn_mfma_f32_16x16x32_bf16(Xf, A0, zero, 0, 0, 0);
        f32x4 d1 = __builtin_amdgcn_mfma_f32_16x16x32_bf16(Xf, A1, zero, 0, 0, 0);

        // lane holds D[hw = hwrow+4g+q][a = r (d0) / r+16 (d1)] -> float4 along hw
        const size_t hwg = (size_t)chunk * 256 + hwrow + 4 * g;
        float* o0 = out + (((size_t)r * BB + b) * CC + c) * HWD + hwg;
        float* o1 = out + (((size_t)(r + 16) * BB + b) * CC + c) * HWD + hwg;
        __builtin_nontemporal_store(d0, (f32x4*)o0);
        __builtin_nontemporal_store(d1, (f32x4*)o1);
    }
}

extern "C" void kernel_launch(void* const* d_in, const int* in_sizes, int n_in,
                              void* d_out, int out_size, void* d_ws, size_t ws_size,
                              hipStream_t stream) {
    const float* x = (const float*)d_in[0];
    const float* w = (const float*)d_in[1];
    float* outp = (float*)d_out;
    float* Gp = (float*)d_ws;                                                  // 4 MB
    unsigned short* Ahat = (unsigned short*)((char*)d_ws + (size_t)4 * 1024 * 1024); // 256 KB

    hipLaunchKernelGGL(k_gram,    dim3(1024), dim3(256), 0, stream, x, Gp);
    hipLaunchKernelGGL(k_softmax, dim3(128),  dim3(256), 0, stream, Gp, w, Ahat);
    hipLaunchKernelGGL(k_pv,      dim3(2048), dim3(256), 0, stream, x, Ahat, outp);
}